// Round 16
// baseline (187.072 us; speedup 1.0000x reference)
//
#include <hip/hip_runtime.h>

// NADE forward, B=512, D=1024, H=512, C=4.
// 3-launch structure (R16):
//   1) k_prep2 : V->bf16 frag pack (h-quartered) + W->WtL / x->xt transposes
//                (verbatim R12/R15; outputs feed k_main only)
//   2) k_pp2   : FUSED partial+prefix at FULL parallelism: 512 blocks x 512
//                threads = 262144 threads = one per (b,h) pair (R11's failed
//                fusion had 32K). Thread (b,h): run=c*L2E; per chunk k stage
//                W[64h x 32d]*L2E and x[8b x 32d] in LDS, acc = j-ascending
//                fmaf chain, store run, run+=acc -- float-identical to the
//                old partial-then-prefix. Deletes the 64 MiB prefix RMW pass,
//                one node, and one gap.
//   3) k_main  : oct-step scan, verbatim R12/R15 (74.5us verified)
// Ledger: R3 prefetch spilled; R4/R5 waves-arg=8 -> 32-VGPR spill; R6 fine
// chunks +22us; R8 W-direct-in-512thr-partial +7us; R9/R10 cadence -4.8
// (kept); R11 k_pp 32K-thread collapse (94us); R13 prologue-prefix O(K^2);
// R14 repack neutral; R15 prefix-MLP -1us (kept, now subsumed).

#define Bv 512
#define Dv 1024
#define Hv 512
#define Cv 4
#define Kv 32
#define DCv 32   // Dv / Kv

#define L2E 1.4426950408889634f
#define LN2 0.6931471805599453f

typedef __attribute__((ext_vector_type(8))) short short8;
typedef __attribute__((ext_vector_type(4))) float f32x4;

__device__ __forceinline__ float fexp2(float x) { return __builtin_amdgcn_exp2f(x); }
__device__ __forceinline__ float flog2(float x) { return __builtin_amdgcn_logf(x); }
__device__ __forceinline__ float frcp(float x)  { return __builtin_amdgcn_rcpf(x); }

// pack two f32 -> bf16x2 by truncation (1 v_perm_b32)
__device__ __forceinline__ unsigned bf16pk(float lo, float hi) {
    return __builtin_amdgcn_perm(__float_as_uint(hi), __float_as_uint(lo), 0x07060302u);
}
__device__ __forceinline__ unsigned short bf16rne(float f) {
    unsigned u = __float_as_uint(f);
    return (unsigned short)((u + 0x7FFFu + ((u >> 16) & 1u)) >> 16);
}

// ---- launch 1: V-pack (h-quartered, 1024 blocks) + transposes (256) ----
__global__ __launch_bounds__(256) void k_prep2(
        const float* __restrict__ W, const float* __restrict__ x,
        const float* __restrict__ V,
        float* __restrict__ WtL, float* __restrict__ xt,
        unsigned short* __restrict__ VtA4) {
    __shared__ __align__(16) char smem[16640];
    const int blk = blockIdx.x;

    if (blk < 1024) {
        // V -> VtA4 fragments (bf16 RNE): block = 4 d x 128 h (h-quarter).
        // VtA4[((d*16 + hb)*16 + q*4 + c)*8 + j], elem = V[h=hb*32+q*8+j][d][c]
        unsigned short* tile = (unsigned short*)smem;   // 2048 shorts
        const int d0 = (blk >> 2) * 4;
        const int hq = blk & 3;             // h-quarter
        const int dd  = threadIdx.x & 3;
        const int hb0 = threadIdx.x >> 2;   // 0..63
#pragma unroll
        for (int p = 0; p < 2; ++p) {
            int h = hq * 128 + p * 64 + hb0;
            float4 v = *(const float4*)(V + ((size_t)h * Dv + d0 + dd) * Cv);
            int hbl = (h >> 5) - hq * 4;    // 0..3 local hb
            int q = (h >> 3) & 3, j = h & 7;
            int base = (dd * 4 + hbl) * 128 + q * 32 + j;
            tile[base + 0 * 8] = bf16rne(v.x);
            tile[base + 1 * 8] = bf16rne(v.y);
            tile[base + 2 * 8] = bf16rne(v.z);
            tile[base + 3 * 8] = bf16rne(v.w);
        }
        __syncthreads();
        {
            const uint4* srcp = (const uint4*)tile;      // 256 uint4
            int tt  = threadIdx.x;
            int dd2 = tt >> 6;
            int off = tt & 63;
            uint4* dst = (uint4*)VtA4;
            dst[(size_t)(d0 + dd2) * 256 + hq * 64 + off] = srcp[dd2 * 64 + off];
        }
    } else {
        // LDS-tiled transposes: WtL[d][h]=W[h][d]*L2E ; xt[d][b]=x[b][d]
        float (*t)[65] = (float(*)[65])smem;
        const int t2   = blk - 1024;         // 0..255
        const int mb   = t2 >> 7;            // 0: W, 1: x
        const int tile = t2 & 127;
        const int tr   = tile >> 4;
        const int tc   = tile & 15;
        const float* src = mb ? x : W;
        float* dst       = mb ? xt : WtL;
        const float scale = mb ? 1.0f : L2E;
        const int lx = threadIdx.x & 15;
        const int ly = threadIdx.x >> 4;
#pragma unroll
        for (int r = 0; r < 64; r += 16) {
            int row = r + ly;
            float4 v = *(const float4*)(src + (size_t)(tr * 64 + row) * Dv + tc * 64 + lx * 4);
            t[row][lx * 4 + 0] = v.x;
            t[row][lx * 4 + 1] = v.y;
            t[row][lx * 4 + 2] = v.z;
            t[row][lx * 4 + 3] = v.w;
        }
        __syncthreads();
#pragma unroll
        for (int r = 0; r < 64; r += 16) {
            int row = r + ly;   // d within tile
            float4 o = make_float4(t[lx * 4 + 0][row] * scale,
                                   t[lx * 4 + 1][row] * scale,
                                   t[lx * 4 + 2][row] * scale,
                                   t[lx * 4 + 3][row] * scale);
            *(float4*)(dst + (size_t)(tc * 64 + row) * 512 + tr * 64 + lx * 4) = o;
        }
    }
}

// ---- launch 2: fused partial+prefix, one thread per (b,h). 512 x 512. ----
// Block = 8 b x 64 h. Per chunk k: stage W-slice*L2E and x-slice in LDS,
// j-ascending fmaf chain, store run, run += acc. Float-identical to the
// old k_partial + k_prefix sequence.
__global__ __launch_bounds__(512) void k_pp2(
        const float* __restrict__ x, const float* __restrict__ W,
        const float* __restrict__ cbias, float* __restrict__ A0) {
    __shared__ float ws[64][33];   // 8.25 KiB  (h_local x d, padded)
    __shared__ float xs[32][8];    // 1 KiB     (d x b_local)
    const int hg = blockIdx.x & 7;     // h-group
    const int bg = blockIdx.x >> 3;    // b-group, 0..63
    const int h0 = hg * 64, b0 = bg * 8;
    const int th = threadIdx.x & 63;   // h_local (wave-contiguous -> coalesced A0 store)
    const int tb = threadIdx.x >> 6;   // b_local 0..7 (uniform per wave -> xs broadcast)
    const int h = h0 + th, b = b0 + tb;

    float run = cbias[h] * L2E;

    for (int k = 0; k < Kv; ++k) {
        const int d0 = k * DCv;
        __syncthreads();   // WAR: previous iteration's reads done
        // stage ws: 64h x 32d, 4 elements/thread, contiguous 128B rows
#pragma unroll
        for (int r = 0; r < 4; ++r) {
            int idx = threadIdx.x + r * 512;
            int i = idx >> 5, j = idx & 31;
            ws[i][j] = W[(size_t)(h0 + i) * Dv + d0 + j] * L2E;
        }
        // stage xs: 8b x 32d, first 256 threads
        if (threadIdx.x < 256) {
            int g = threadIdx.x >> 5, j = threadIdx.x & 31;
            xs[j][g] = x[(size_t)(b0 + g) * Dv + d0 + j];
        }
        __syncthreads();
        float acc = 0.0f;
#pragma unroll
        for (int j = 0; j < DCv; ++j)
            acc = fmaf(xs[j][tb], ws[th][j], acc);
        A0[(size_t)k * Bv * Hv + (size_t)b * Hv + h] = run;
        run += acc;
    }
}

// ---- launch 3: main scan, OCT-step (verbatim R12/R15, 74.5us verified). ----
__global__ __launch_bounds__(256, 4) void k_main(
        const float* __restrict__ xt, const float* __restrict__ bbias,
        const unsigned short* __restrict__ VtA4, const float* __restrict__ WtL,
        const float* __restrict__ A0, float* __restrict__ out) {
    const int k    = blockIdx.x >> 5;
    const int bg   = blockIdx.x & 31;
    const int wid  = threadIdx.x >> 6;   // H-slice owner
    const int lane = threadIdx.x & 63;
    const int bl   = lane & 15;          // batch col (B-op) / class row m (A-op)
    const int quad = lane >> 4;
    const int b    = bg * 16 + bl;
    const int d0   = k * DCv;

    // only quad==0 lanes carry nonzero C rows (classes 0..3) -> 16 batches/step
    __shared__ f32x4 red[2][8][4][16];   // [buf][step][wid][batch], 16 KiB

    // a state: h = wid*128 + kb*32 + quad*8 + j (scaled domain)
    float a[32];
    {
        const float* ap = A0 + ((size_t)k * Bv + b) * Hv + wid * 128 + quad * 8;
#pragma unroll
        for (int kb = 0; kb < 4; ++kb) {
            float4 t0 = *(const float4*)(ap + kb * 32);
            float4 t1 = *(const float4*)(ap + kb * 32 + 4);
            a[kb*8+0]=t0.x; a[kb*8+1]=t0.y; a[kb*8+2]=t0.z; a[kb*8+3]=t0.w;
            a[kb*8+4]=t1.x; a[kb*8+5]=t1.y; a[kb*8+6]=t1.z; a[kb*8+7]=t1.w;
        }
    }

    const bool act = (bl < 4);
    const unsigned short* vp = VtA4 + (((size_t)d0 * 16 + wid * 4) * 16 + quad * 4 + bl) * 8;
    const float* wp = WtL + (size_t)d0 * Hv + wid * 128 + quad * 8;
    const float* xp = xt + (size_t)d0 * Bv + b;

    // epilogue: wave wid finalizes steps {2wid, 2wid+1};
    // lanes 0-15 -> step 2wid, lanes 32-47 -> step 2wid+1.
    const int  sE  = wid * 2 + (lane >> 5);          // 0..7
    const bool epi = ((lane >> 4) & 1) == 0;         // quads 0 and 2
    const float* bpE = bbias + (d0 + sE) * Cv;
    float* spY = out + (size_t)b * Dv * Cv + (d0 + sE) * Cv;
    float* spP = spY + (size_t)Bv * Dv * Cv;

    const short8 zfrag = {0,0,0,0,0,0,0,0};

    for (int i1 = 0; i1 < DCv / 8; ++i1) {       // 4 iterations, 1 barrier each
        const int buf = i1 & 1;
#pragma unroll 1
        for (int half = 0; half < 2; ++half) {
#pragma unroll
            for (int s = 0; s < 4; ++s) {
                // this step's fragments + scalar (one step live at a time)
                short8 af[4];
#pragma unroll
                for (int kb = 0; kb < 4; ++kb)
                    af[kb] = act ? *(const short8*)(vp + s * 2048 + kb * 128) : zfrag;
                float xd = xp[s * Bv];

                // sigmoid + pack
                unsigned pk[16];
#pragma unroll
                for (int m = 0; m < 32; m += 2) {
                    float s0 = frcp(1.0f + fexp2(-a[m]));
                    float s1 = frcp(1.0f + fexp2(-a[m + 1]));
                    pk[m >> 1] = bf16pk(s0, s1);
                }
                // MFMA over the wave's 128-h slice
                f32x4 acc = {0.f, 0.f, 0.f, 0.f};
#pragma unroll
                for (int kb = 0; kb < 4; ++kb) {
                    union { unsigned u[4]; short8 s8; } cv;
                    cv.u[0] = pk[kb*4+0]; cv.u[1] = pk[kb*4+1];
                    cv.u[2] = pk[kb*4+2]; cv.u[3] = pk[kb*4+3];
                    acc = __builtin_amdgcn_mfma_f32_16x16x32_bf16(af[kb], cv.s8, acc, 0, 0, 0);
                }
                // advance a to next step
#pragma unroll
                for (int kb = 0; kb < 4; ++kb)
#pragma unroll
                    for (int j = 0; j < 8; ++j)
                        a[kb*8+j] = fmaf(xd, wp[s * Hv + kb*32 + j], a[kb*8+j]);

                if (quad == 0) red[buf][half * 4 + s][wid][bl] = acc;
            }
            vp += 4 * 2048;
            wp += 4 * Hv;
            xp += 4 * Bv;
        }
        __syncthreads();

        // ---- epilogue: 8 steps finalized by 4 waves x 2 half-lane groups ----
        if (epi) {
            float4 bbv = *(const float4*)bpE;
            f32x4 r0 = red[buf][sE][0][bl];
            f32x4 r1 = red[buf][sE][1][bl];
            f32x4 r2 = red[buf][sE][2][bl];
            f32x4 r3 = red[buf][sE][3][bl];
            float w0 = r0.x + r1.x + r2.x + r3.x + bbv.x;
            float w1 = r0.y + r1.y + r2.y + r3.y + bbv.y;
            float w2 = r0.z + r1.z + r2.z + r3.z + bbv.z;
            float w3 = r0.w + r1.w + r2.w + r3.w + bbv.w;
            *(float4*)spY = make_float4(w0, w1, w2, w3);
            float mx = fmaxf(fmaxf(w0, w1), fmaxf(w2, w3));
            float e0 = fexp2((w0 - mx) * L2E);
            float e1 = fexp2((w1 - mx) * L2E);
            float e2 = fexp2((w2 - mx) * L2E);
            float e3 = fexp2((w3 - mx) * L2E);
            float lse = mx + flog2(e0 + e1 + e2 + e3) * LN2;
            *(float4*)spP = make_float4(w0 - lse, w1 - lse, w2 - lse, w3 - lse);
        }

        bpE += 8 * Cv;
        spY += 8 * Cv;
        spP += 8 * Cv;
    }
}

extern "C" void kernel_launch(void* const* d_in, const int* in_sizes, int n_in,
                              void* d_out, int out_size, void* d_ws, size_t ws_size,
                              hipStream_t stream) {
    const float* x  = (const float*)d_in[0];   // [B, D]
    const float* V  = (const float*)d_in[1];   // [H, D, C]
    const float* bb = (const float*)d_in[2];   // [D, C]
    const float* W  = (const float*)d_in[3];   // [H, D]
    const float* cb = (const float*)d_in[4];   // [1, H]
    float* out = (float*)d_out;                // y_hat [B*D*C] then p_hat

    char* ws = (char*)d_ws;
    unsigned short* VtA4 = (unsigned short*)ws;                 // 4 MiB
    float* WtL = (float*)(ws + (size_t)4 * 1024 * 1024);        // 2 MiB
    float* xt  = (float*)(ws + (size_t)6 * 1024 * 1024);        // 2 MiB
    float* A0  = (float*)(ws + (size_t)8 * 1024 * 1024);        // 32 MiB (K*B*H)

    k_prep2<<<1280, 256, 0, stream>>>(W, x, V, WtL, xt, VtA4);
    k_pp2<<<512, 512, 0, stream>>>(x, W, cb, A0);
    k_main<<<Kv * 32, 256, 0, stream>>>(xt, bb, VtA4, WtL, A0, out);
}

// Round 17
// 171.200 us; speedup vs baseline: 1.0927x; 1.0927x over previous
//
#include <hip/hip_runtime.h>

// NADE forward, B=512, D=1024, H=512, C=4.
// 4-launch structure (pre-kernels verbatim R15 = verified-best complement):
//   1) k_prep2  : V->bf16 frag pack (h-quartered) + W/x transposes
//   2) k_partial: A0 chunk partials (verbatim R0)
//   3) k_prefix : exclusive prefix, 32 loads preloaded (R15)
//   4) k_main   : R5's 8-wave x 64-h-slice scan, but with PLAIN
//                 __launch_bounds__(512) -- R5 failed ONLY from the
//                 (512,8) attribute's 32-VGPR budget (proven spill
//                 mechanism, R4+R5). Natural ~40-48 VGPR -> 8 waves/SIMD
//                 possible at grid 1024 = 2x R15's residency for the
//                 trans-pipe-bound loop.
// Ledger: R3 prefetch spill; R4/R5 waves-arg=8 spill; R6 fine-chunks +22;
// R8 W-direct +7; R9/R10 cadence -4.8; R11/R16 partial+prefix fusions lose;
// R13 prologue-prefix O(K^2); R14 repack neutral; R15 prefix-MLP -1 (kept).

#define Bv 512
#define Dv 1024
#define Hv 512
#define Cv 4
#define Kv 32
#define DCv 32   // Dv / Kv

#define L2E 1.4426950408889634f
#define LN2 0.6931471805599453f

typedef __attribute__((ext_vector_type(8))) short short8;
typedef __attribute__((ext_vector_type(4))) float f32x4;

__device__ __forceinline__ float fexp2(float x) { return __builtin_amdgcn_exp2f(x); }
__device__ __forceinline__ float flog2(float x) { return __builtin_amdgcn_logf(x); }
__device__ __forceinline__ float frcp(float x)  { return __builtin_amdgcn_rcpf(x); }

// pack two f32 -> bf16x2 by truncation (1 v_perm_b32)
__device__ __forceinline__ unsigned bf16pk(float lo, float hi) {
    return __builtin_amdgcn_perm(__float_as_uint(hi), __float_as_uint(lo), 0x07060302u);
}
__device__ __forceinline__ unsigned short bf16rne(float f) {
    unsigned u = __float_as_uint(f);
    return (unsigned short)((u + 0x7FFFu + ((u >> 16) & 1u)) >> 16);
}

// ---- launch 1: V-pack (h-quartered, 1024 blocks) + transposes (256) ----
__global__ __launch_bounds__(256) void k_prep2(
        const float* __restrict__ W, const float* __restrict__ x,
        const float* __restrict__ V,
        float* __restrict__ WtL, float* __restrict__ xt,
        unsigned short* __restrict__ VtA4) {
    __shared__ __align__(16) char smem[16640];
    const int blk = blockIdx.x;

    if (blk < 1024) {
        // V -> VtA4 fragments (bf16 RNE): block = 4 d x 128 h (h-quarter).
        // VtA4[((d*16 + hb)*16 + q*4 + c)*8 + j], elem = V[h=hb*32+q*8+j][d][c]
        unsigned short* tile = (unsigned short*)smem;   // 2048 shorts
        const int d0 = (blk >> 2) * 4;
        const int hq = blk & 3;             // h-quarter
        const int dd  = threadIdx.x & 3;
        const int hb0 = threadIdx.x >> 2;   // 0..63
#pragma unroll
        for (int p = 0; p < 2; ++p) {
            int h = hq * 128 + p * 64 + hb0;
            float4 v = *(const float4*)(V + ((size_t)h * Dv + d0 + dd) * Cv);
            int hbl = (h >> 5) - hq * 4;    // 0..3 local hb
            int q = (h >> 3) & 3, j = h & 7;
            int base = (dd * 4 + hbl) * 128 + q * 32 + j;
            tile[base + 0 * 8] = bf16rne(v.x);
            tile[base + 1 * 8] = bf16rne(v.y);
            tile[base + 2 * 8] = bf16rne(v.z);
            tile[base + 3 * 8] = bf16rne(v.w);
        }
        __syncthreads();
        {
            const uint4* srcp = (const uint4*)tile;      // 256 uint4
            int tt  = threadIdx.x;
            int dd2 = tt >> 6;
            int off = tt & 63;
            uint4* dst = (uint4*)VtA4;
            dst[(size_t)(d0 + dd2) * 256 + hq * 64 + off] = srcp[dd2 * 64 + off];
        }
    } else {
        // LDS-tiled transposes: WtL[d][h]=W[h][d]*L2E ; xt[d][b]=x[b][d]
        float (*t)[65] = (float(*)[65])smem;
        const int t2   = blk - 1024;         // 0..255
        const int mb   = t2 >> 7;            // 0: W, 1: x
        const int tile = t2 & 127;
        const int tr   = tile >> 4;
        const int tc   = tile & 15;
        const float* src = mb ? x : W;
        float* dst       = mb ? xt : WtL;
        const float scale = mb ? 1.0f : L2E;
        const int lx = threadIdx.x & 15;
        const int ly = threadIdx.x >> 4;
#pragma unroll
        for (int r = 0; r < 64; r += 16) {
            int row = r + ly;
            float4 v = *(const float4*)(src + (size_t)(tr * 64 + row) * Dv + tc * 64 + lx * 4);
            t[row][lx * 4 + 0] = v.x;
            t[row][lx * 4 + 1] = v.y;
            t[row][lx * 4 + 2] = v.z;
            t[row][lx * 4 + 3] = v.w;
        }
        __syncthreads();
#pragma unroll
        for (int r = 0; r < 64; r += 16) {
            int row = r + ly;   // d within tile
            float4 o = make_float4(t[lx * 4 + 0][row] * scale,
                                   t[lx * 4 + 1][row] * scale,
                                   t[lx * 4 + 2][row] * scale,
                                   t[lx * 4 + 3][row] * scale);
            *(float4*)(dst + (size_t)(tc * 64 + row) * 512 + tr * 64 + lx * 4) = o;
        }
    }
}

// ---- launch 2: chunk partials into A0 (verbatim R0 k_partial) ----
__global__ __launch_bounds__(512) void k_partial(const float* __restrict__ x,
                          const float* __restrict__ WtL, float* __restrict__ A0) {
    int k  = blockIdx.x >> 6;
    int bg = blockIdx.x & 63;
    int h  = threadIdx.x;
    int d0 = k * DCv;

    __shared__ float xs[DCv * 8];
    if (threadIdx.x < DCv * 8) {
        int g = threadIdx.x >> 5;   // batch in group of 8
        int j = threadIdx.x & 31;   // d in chunk
        xs[j * 8 + g] = x[(size_t)(bg * 8 + g) * Dv + d0 + j];
    }
    __syncthreads();

    float acc[8];
#pragma unroll
    for (int g = 0; g < 8; ++g) acc[g] = 0.0f;

    const float* wp = WtL + (size_t)d0 * Hv + h;
    for (int j = 0; j < DCv; ++j) {
        float wv = wp[(size_t)j * Hv];
        const float4 x0 = *(const float4*)(xs + j * 8);
        const float4 x1 = *(const float4*)(xs + j * 8 + 4);
        acc[0] = fmaf(x0.x, wv, acc[0]);
        acc[1] = fmaf(x0.y, wv, acc[1]);
        acc[2] = fmaf(x0.z, wv, acc[2]);
        acc[3] = fmaf(x0.w, wv, acc[3]);
        acc[4] = fmaf(x1.x, wv, acc[4]);
        acc[5] = fmaf(x1.y, wv, acc[5]);
        acc[6] = fmaf(x1.z, wv, acc[6]);
        acc[7] = fmaf(x1.w, wv, acc[7]);
    }
#pragma unroll
    for (int g = 0; g < 8; ++g)
        A0[((size_t)k * Bv + bg * 8 + g) * Hv + h] = acc[g];
}

// ---- launch 3: exclusive prefix, loads fully preloaded (verbatim R15) ----
__global__ void k_prefix(float* __restrict__ A0, const float* __restrict__ cbias) {
    int gid = blockIdx.x * blockDim.x + threadIdx.x;   // B*H
    int h = gid & (Hv - 1);
    int bi = gid >> 9;
    float* p = A0 + (size_t)bi * Hv + h;

    float t[Kv];
#pragma unroll
    for (int k = 0; k < Kv; ++k)
        t[k] = p[(size_t)k * Bv * Hv];

    float run = cbias[h] * L2E;
#pragma unroll
    for (int k = 0; k < Kv; ++k) {
        p[(size_t)k * Bv * Hv] = run;
        run += t[k];
    }
}

// ---- launch 4: main scan. 512-thr blocks, 8 waves x 64-h slices (R5 body,
// PLAIN launch_bounds -- no waves-arg register cap). ----
__global__ __launch_bounds__(512) void k_main(
        const float* __restrict__ xt, const float* __restrict__ bbias,
        const unsigned short* __restrict__ VtA4, const float* __restrict__ WtL,
        const float* __restrict__ A0, float* __restrict__ out) {
    const int k    = blockIdx.x >> 5;    // chunk 0..31
    const int bg   = blockIdx.x & 31;
    const int wid  = threadIdx.x >> 6;   // 0..7: H-slice of 64
    const int lane = threadIdx.x & 63;
    const int bl   = lane & 15;          // batch col (B-op) / class row m (A-op)
    const int quad = lane >> 4;
    const int b    = bg * 16 + bl;
    const int d0   = k * DCv;
    const int stp  = wid >> 1;           // epilogue role (waves 0..3 only)
    const bool isP = wid & 1;
    const bool epi = (wid < 4);

    __shared__ f32x4 red[2][2][8][64];   // [pairbuf][step][wid][lane], 32 KiB

    // a state: h = wid*64 + kb*32 + quad*8 + j (scaled domain), kb in {0,1}
    float a[16];
    {
        const float* ap = A0 + ((size_t)k * Bv + b) * Hv + wid * 64 + quad * 8;
#pragma unroll
        for (int kb = 0; kb < 2; ++kb) {
            float4 t0 = *(const float4*)(ap + kb * 32);
            float4 t1 = *(const float4*)(ap + kb * 32 + 4);
            a[kb*8+0]=t0.x; a[kb*8+1]=t0.y; a[kb*8+2]=t0.z; a[kb*8+3]=t0.w;
            a[kb*8+4]=t1.x; a[kb*8+5]=t1.y; a[kb*8+6]=t1.z; a[kb*8+7]=t1.w;
        }
    }

    const bool act = (bl < 4);
    // hb = h>>5 = wid*2 + kb
    const unsigned short* vp = VtA4 + (((size_t)d0 * 16 + wid * 2) * 16 + quad * 4 + bl) * 8;
    const float* wp = WtL + (size_t)d0 * Hv + wid * 64 + quad * 8;
    const float* xp = xt + (size_t)d0 * Bv + b;
    const float* bp = bbias + (d0 + (stp & 1)) * Cv;    // valid for epi waves
    float* sp = out + (isP ? (size_t)Bv * Dv * Cv : (size_t)0)
                    + (size_t)b * Dv * Cv + (d0 + (stp & 1)) * Cv;

    const short8 zfrag = {0,0,0,0,0,0,0,0};

    for (int i1 = 0; i1 < DCv / 2; ++i1) {
        // fragment / scalar loads for both steps of the pair
        short8 afA[2], afB[2];
#pragma unroll
        for (int kb = 0; kb < 2; ++kb)
            afA[kb] = act ? *(const short8*)(vp + kb * 128) : zfrag;
#pragma unroll
        for (int kb = 0; kb < 2; ++kb)
            afB[kb] = act ? *(const short8*)(vp + 2048 + kb * 128) : zfrag;
        float xdA = xp[0];
        float xdB = xp[Bv];
        float4 bbv = epi ? *(const float4*)bp : make_float4(0.f, 0.f, 0.f, 0.f);

        // ---- step A: sigmoid + pack + MFMA ----
        unsigned pkA[8];
#pragma unroll
        for (int m = 0; m < 16; m += 2) {
            float s0 = frcp(1.0f + fexp2(-a[m]));
            float s1 = frcp(1.0f + fexp2(-a[m + 1]));
            pkA[m >> 1] = bf16pk(s0, s1);
        }
        f32x4 accA = {0.f, 0.f, 0.f, 0.f};
#pragma unroll
        for (int kb = 0; kb < 2; ++kb) {
            union { unsigned u[4]; short8 s; } cv;
            cv.u[0] = pkA[kb*4+0]; cv.u[1] = pkA[kb*4+1];
            cv.u[2] = pkA[kb*4+2]; cv.u[3] = pkA[kb*4+3];
            accA = __builtin_amdgcn_mfma_f32_16x16x32_bf16(afA[kb], cv.s, accA, 0, 0, 0);
        }
        // advance a to step B
#pragma unroll
        for (int kb = 0; kb < 2; ++kb)
#pragma unroll
            for (int j = 0; j < 8; ++j)
                a[kb*8+j] = fmaf(xdA, wp[kb*32+j], a[kb*8+j]);

        // ---- step B: sigmoid + pack + MFMA ----
        unsigned pkB[8];
#pragma unroll
        for (int m = 0; m < 16; m += 2) {
            float s0 = frcp(1.0f + fexp2(-a[m]));
            float s1 = frcp(1.0f + fexp2(-a[m + 1]));
            pkB[m >> 1] = bf16pk(s0, s1);
        }
        f32x4 accB = {0.f, 0.f, 0.f, 0.f};
#pragma unroll
        for (int kb = 0; kb < 2; ++kb) {
            union { unsigned u[4]; short8 s; } cv;
            cv.u[0] = pkB[kb*4+0]; cv.u[1] = pkB[kb*4+1];
            cv.u[2] = pkB[kb*4+2]; cv.u[3] = pkB[kb*4+3];
            accB = __builtin_amdgcn_mfma_f32_16x16x32_bf16(afB[kb], cv.s, accB, 0, 0, 0);
        }
        // advance a to next pair
#pragma unroll
        for (int kb = 0; kb < 2; ++kb)
#pragma unroll
            for (int j = 0; j < 8; ++j)
                a[kb*8+j] = fmaf(xdB, wp[Hv + kb*32+j], a[kb*8+j]);

        // ---- cross-wave reduce: one barrier per pair ----
        const int buf = i1 & 1;
        red[buf][0][wid][lane] = accA;
        red[buf][1][wid][lane] = accB;
        __syncthreads();

        if (epi) {
            f32x4 s = red[buf][stp][0][lane];
#pragma unroll
            for (int w = 1; w < 8; ++w) {
                f32x4 r = red[buf][stp][w][lane];
                s.x += r.x; s.y += r.y; s.z += r.z; s.w += r.w;
            }
            float w0 = s.x + bbv.x;
            float w1 = s.y + bbv.y;
            float w2 = s.z + bbv.z;
            float w3 = s.w + bbv.w;

            if (!isP) {
                if (quad == 0) *(float4*)sp = make_float4(w0, w1, w2, w3);
            } else {
                float mx = fmaxf(fmaxf(w0, w1), fmaxf(w2, w3));
                float e0 = fexp2((w0 - mx) * L2E);
                float e1 = fexp2((w1 - mx) * L2E);
                float e2 = fexp2((w2 - mx) * L2E);
                float e3 = fexp2((w3 - mx) * L2E);
                float lse = mx + flog2(e0 + e1 + e2 + e3) * LN2;
                if (quad == 0)
                    *(float4*)sp = make_float4(w0 - lse, w1 - lse, w2 - lse, w3 - lse);
            }
        }

        vp += 2 * 2048;    // 2 d-steps
        wp += 2 * Hv;
        xp += 2 * Bv;
        bp += 2 * Cv;
        sp += 2 * Cv;
    }
}

extern "C" void kernel_launch(void* const* d_in, const int* in_sizes, int n_in,
                              void* d_out, int out_size, void* d_ws, size_t ws_size,
                              hipStream_t stream) {
    const float* x  = (const float*)d_in[0];   // [B, D]
    const float* V  = (const float*)d_in[1];   // [H, D, C]
    const float* bb = (const float*)d_in[2];   // [D, C]
    const float* W  = (const float*)d_in[3];   // [H, D]
    const float* cb = (const float*)d_in[4];   // [1, H]
    float* out = (float*)d_out;                // y_hat [B*D*C] then p_hat

    char* ws = (char*)d_ws;
    unsigned short* VtA4 = (unsigned short*)ws;                 // 4 MiB
    float* WtL = (float*)(ws + (size_t)4 * 1024 * 1024);        // 2 MiB
    float* xt  = (float*)(ws + (size_t)6 * 1024 * 1024);        // 2 MiB
    float* A0  = (float*)(ws + (size_t)8 * 1024 * 1024);        // 32 MiB (K*B*H)

    k_prep2<<<1280, 256, 0, stream>>>(W, x, V, WtL, xt, VtA4);
    k_partial<<<Kv * (Bv / 8), 512, 0, stream>>>(x, WtL, A0);
    k_prefix<<<(Bv * Hv) / 256, 256, 0, stream>>>(A0, cb);
    k_main<<<Kv * 32, 512, 0, stream>>>(xt, bb, VtA4, WtL, A0, out);
}

// Round 18
// 162.877 us; speedup vs baseline: 1.1485x; 1.0511x over previous
//
#include <hip/hip_runtime.h>

// NADE forward, B=512, D=1024, H=512, C=4.
// 4-launch structure (pre-kernels verbatim R15 = verified-best complement):
//   1) k_prep2  : V->bf16 frag pack (h-quartered) + W/x transposes
//   2) k_partial: A0 chunk partials (verbatim R0)
//   3) k_prefix : exclusive prefix, 32 loads preloaded (R15)
//   4) k_main   : 16 d-steps per barrier (2 barriers/chunk) -- the final
//                 rung of the cadence ladder (16->8: -3.4us, 8->4: -1.4us).
//                 This exact body passed correctness in R11; never measured
//                 on the best pre-kernel set. All-64-lane epilogue.
// Ledger: R3 prefetch spill; R4/R5 waves-arg=8 spill; R6 fine-chunks +22;
// R8 W-direct +7; R11/R16 partial+prefix fusions lose; R13 prologue-prefix
// O(K^2); R14 repack neutral; R15 prefix-MLP -1 (kept); R17 8-wave k_main
// +7.4us (NOT residency-bound -- 4-wave oct structure is the optimum base).

#define Bv 512
#define Dv 1024
#define Hv 512
#define Cv 4
#define Kv 32
#define DCv 32   // Dv / Kv

#define L2E 1.4426950408889634f
#define LN2 0.6931471805599453f

typedef __attribute__((ext_vector_type(8))) short short8;
typedef __attribute__((ext_vector_type(4))) float f32x4;

__device__ __forceinline__ float fexp2(float x) { return __builtin_amdgcn_exp2f(x); }
__device__ __forceinline__ float flog2(float x) { return __builtin_amdgcn_logf(x); }
__device__ __forceinline__ float frcp(float x)  { return __builtin_amdgcn_rcpf(x); }

// pack two f32 -> bf16x2 by truncation (1 v_perm_b32)
__device__ __forceinline__ unsigned bf16pk(float lo, float hi) {
    return __builtin_amdgcn_perm(__float_as_uint(hi), __float_as_uint(lo), 0x07060302u);
}
__device__ __forceinline__ unsigned short bf16rne(float f) {
    unsigned u = __float_as_uint(f);
    return (unsigned short)((u + 0x7FFFu + ((u >> 16) & 1u)) >> 16);
}

// ---- launch 1: V-pack (h-quartered, 1024 blocks) + transposes (256) ----
__global__ __launch_bounds__(256) void k_prep2(
        const float* __restrict__ W, const float* __restrict__ x,
        const float* __restrict__ V,
        float* __restrict__ WtL, float* __restrict__ xt,
        unsigned short* __restrict__ VtA4) {
    __shared__ __align__(16) char smem[16640];
    const int blk = blockIdx.x;

    if (blk < 1024) {
        // V -> VtA4 fragments (bf16 RNE): block = 4 d x 128 h (h-quarter).
        // VtA4[((d*16 + hb)*16 + q*4 + c)*8 + j], elem = V[h=hb*32+q*8+j][d][c]
        unsigned short* tile = (unsigned short*)smem;   // 2048 shorts
        const int d0 = (blk >> 2) * 4;
        const int hq = blk & 3;             // h-quarter
        const int dd  = threadIdx.x & 3;
        const int hb0 = threadIdx.x >> 2;   // 0..63
#pragma unroll
        for (int p = 0; p < 2; ++p) {
            int h = hq * 128 + p * 64 + hb0;
            float4 v = *(const float4*)(V + ((size_t)h * Dv + d0 + dd) * Cv);
            int hbl = (h >> 5) - hq * 4;    // 0..3 local hb
            int q = (h >> 3) & 3, j = h & 7;
            int base = (dd * 4 + hbl) * 128 + q * 32 + j;
            tile[base + 0 * 8] = bf16rne(v.x);
            tile[base + 1 * 8] = bf16rne(v.y);
            tile[base + 2 * 8] = bf16rne(v.z);
            tile[base + 3 * 8] = bf16rne(v.w);
        }
        __syncthreads();
        {
            const uint4* srcp = (const uint4*)tile;      // 256 uint4
            int tt  = threadIdx.x;
            int dd2 = tt >> 6;
            int off = tt & 63;
            uint4* dst = (uint4*)VtA4;
            dst[(size_t)(d0 + dd2) * 256 + hq * 64 + off] = srcp[dd2 * 64 + off];
        }
    } else {
        // LDS-tiled transposes: WtL[d][h]=W[h][d]*L2E ; xt[d][b]=x[b][d]
        float (*t)[65] = (float(*)[65])smem;
        const int t2   = blk - 1024;         // 0..255
        const int mb   = t2 >> 7;            // 0: W, 1: x
        const int tile = t2 & 127;
        const int tr   = tile >> 4;
        const int tc   = tile & 15;
        const float* src = mb ? x : W;
        float* dst       = mb ? xt : WtL;
        const float scale = mb ? 1.0f : L2E;
        const int lx = threadIdx.x & 15;
        const int ly = threadIdx.x >> 4;
#pragma unroll
        for (int r = 0; r < 64; r += 16) {
            int row = r + ly;
            float4 v = *(const float4*)(src + (size_t)(tr * 64 + row) * Dv + tc * 64 + lx * 4);
            t[row][lx * 4 + 0] = v.x;
            t[row][lx * 4 + 1] = v.y;
            t[row][lx * 4 + 2] = v.z;
            t[row][lx * 4 + 3] = v.w;
        }
        __syncthreads();
#pragma unroll
        for (int r = 0; r < 64; r += 16) {
            int row = r + ly;   // d within tile
            float4 o = make_float4(t[lx * 4 + 0][row] * scale,
                                   t[lx * 4 + 1][row] * scale,
                                   t[lx * 4 + 2][row] * scale,
                                   t[lx * 4 + 3][row] * scale);
            *(float4*)(dst + (size_t)(tc * 64 + row) * 512 + tr * 64 + lx * 4) = o;
        }
    }
}

// ---- launch 2: chunk partials into A0 (verbatim R0 k_partial) ----
__global__ __launch_bounds__(512) void k_partial(const float* __restrict__ x,
                          const float* __restrict__ WtL, float* __restrict__ A0) {
    int k  = blockIdx.x >> 6;
    int bg = blockIdx.x & 63;
    int h  = threadIdx.x;
    int d0 = k * DCv;

    __shared__ float xs[DCv * 8];
    if (threadIdx.x < DCv * 8) {
        int g = threadIdx.x >> 5;   // batch in group of 8
        int j = threadIdx.x & 31;   // d in chunk
        xs[j * 8 + g] = x[(size_t)(bg * 8 + g) * Dv + d0 + j];
    }
    __syncthreads();

    float acc[8];
#pragma unroll
    for (int g = 0; g < 8; ++g) acc[g] = 0.0f;

    const float* wp = WtL + (size_t)d0 * Hv + h;
    for (int j = 0; j < DCv; ++j) {
        float wv = wp[(size_t)j * Hv];
        const float4 x0 = *(const float4*)(xs + j * 8);
        const float4 x1 = *(const float4*)(xs + j * 8 + 4);
        acc[0] = fmaf(x0.x, wv, acc[0]);
        acc[1] = fmaf(x0.y, wv, acc[1]);
        acc[2] = fmaf(x0.z, wv, acc[2]);
        acc[3] = fmaf(x0.w, wv, acc[3]);
        acc[4] = fmaf(x1.x, wv, acc[4]);
        acc[5] = fmaf(x1.y, wv, acc[5]);
        acc[6] = fmaf(x1.z, wv, acc[6]);
        acc[7] = fmaf(x1.w, wv, acc[7]);
    }
#pragma unroll
    for (int g = 0; g < 8; ++g)
        A0[((size_t)k * Bv + bg * 8 + g) * Hv + h] = acc[g];
}

// ---- launch 3: exclusive prefix, loads fully preloaded (verbatim R15) ----
__global__ void k_prefix(float* __restrict__ A0, const float* __restrict__ cbias) {
    int gid = blockIdx.x * blockDim.x + threadIdx.x;   // B*H
    int h = gid & (Hv - 1);
    int bi = gid >> 9;
    float* p = A0 + (size_t)bi * Hv + h;

    float t[Kv];
#pragma unroll
    for (int k = 0; k < Kv; ++k)
        t[k] = p[(size_t)k * Bv * Hv];

    float run = cbias[h] * L2E;
#pragma unroll
    for (int k = 0; k < Kv; ++k) {
        p[(size_t)k * Bv * Hv] = run;
        run += t[k];
    }
}

// ---- launch 4: main scan, 16 d-steps per barrier (2 barriers/chunk). ----
__global__ __launch_bounds__(256, 4) void k_main(
        const float* __restrict__ xt, const float* __restrict__ bbias,
        const unsigned short* __restrict__ VtA4, const float* __restrict__ WtL,
        const float* __restrict__ A0, float* __restrict__ out) {
    const int k    = blockIdx.x >> 5;
    const int bg   = blockIdx.x & 31;
    const int wid  = threadIdx.x >> 6;   // H-slice owner
    const int lane = threadIdx.x & 63;
    const int bl   = lane & 15;          // batch col (B-op) / class row m (A-op)
    const int quad = lane >> 4;
    const int b    = bg * 16 + bl;
    const int d0   = k * DCv;

    // only quad==0 lanes carry nonzero C rows (A rows 4..15 are zero)
    __shared__ f32x4 red[2][16][4][16];  // [buf][step][wid][batch], 32 KiB

    // a state: h = wid*128 + kb*32 + quad*8 + j (scaled domain)
    float a[32];
    {
        const float* ap = A0 + ((size_t)k * Bv + b) * Hv + wid * 128 + quad * 8;
#pragma unroll
        for (int kb = 0; kb < 4; ++kb) {
            float4 t0 = *(const float4*)(ap + kb * 32);
            float4 t1 = *(const float4*)(ap + kb * 32 + 4);
            a[kb*8+0]=t0.x; a[kb*8+1]=t0.y; a[kb*8+2]=t0.z; a[kb*8+3]=t0.w;
            a[kb*8+4]=t1.x; a[kb*8+5]=t1.y; a[kb*8+6]=t1.z; a[kb*8+7]=t1.w;
        }
    }

    const bool act = (bl < 4);
    const unsigned short* vp = VtA4 + (((size_t)d0 * 16 + wid * 4) * 16 + quad * 4 + bl) * 8;
    const float* wp = WtL + (size_t)d0 * Hv + wid * 128 + quad * 8;
    const float* xp = xt + (size_t)d0 * Bv + b;

    const short8 zfrag = {0,0,0,0,0,0,0,0};

    for (int i1 = 0; i1 < 2; ++i1) {             // 2 iterations, 1 barrier each
        const int buf = i1 & 1;
#pragma unroll 1
        for (int q4 = 0; q4 < 4; ++q4) {
#pragma unroll
            for (int s = 0; s < 4; ++s) {
                // this step's fragments + scalar (one step live at a time)
                short8 af[4];
#pragma unroll
                for (int kb = 0; kb < 4; ++kb)
                    af[kb] = act ? *(const short8*)(vp + s * 2048 + kb * 128) : zfrag;
                float xd = xp[s * Bv];

                // sigmoid + pack
                unsigned pk[16];
#pragma unroll
                for (int m = 0; m < 32; m += 2) {
                    float s0 = frcp(1.0f + fexp2(-a[m]));
                    float s1 = frcp(1.0f + fexp2(-a[m + 1]));
                    pk[m >> 1] = bf16pk(s0, s1);
                }
                // MFMA over the wave's 128-h slice
                f32x4 acc = {0.f, 0.f, 0.f, 0.f};
#pragma unroll
                for (int kb = 0; kb < 4; ++kb) {
                    union { unsigned u[4]; short8 s8; } cv;
                    cv.u[0] = pk[kb*4+0]; cv.u[1] = pk[kb*4+1];
                    cv.u[2] = pk[kb*4+2]; cv.u[3] = pk[kb*4+3];
                    acc = __builtin_amdgcn_mfma_f32_16x16x32_bf16(af[kb], cv.s8, acc, 0, 0, 0);
                }
                // advance a to next step (same fmaf sequence as R9/R10)
#pragma unroll
                for (int kb = 0; kb < 4; ++kb)
#pragma unroll
                    for (int j = 0; j < 8; ++j)
                        a[kb*8+j] = fmaf(xd, wp[s * Hv + kb*32 + j], a[kb*8+j]);

                if (quad == 0) red[buf][q4 * 4 + s][wid][bl] = acc;
            }
            vp += 4 * 2048;
            wp += 4 * Hv;
            xp += 4 * Bv;
        }
        __syncthreads();

        // ---- epilogue: 16 steps, all 64 lanes: quad q -> step wid*4+q ----
        {
            const int sE = wid * 4 + quad;          // 0..15
            const int dd = d0 + i1 * 16 + sE;       // global d of this step
            float4 bbv = *(const float4*)(bbias + dd * Cv);
            f32x4 r0 = red[buf][sE][0][bl];
            f32x4 r1 = red[buf][sE][1][bl];
            f32x4 r2 = red[buf][sE][2][bl];
            f32x4 r3 = red[buf][sE][3][bl];
            float w0 = r0.x + r1.x + r2.x + r3.x + bbv.x;
            float w1 = r0.y + r1.y + r2.y + r3.y + bbv.y;
            float w2 = r0.z + r1.z + r2.z + r3.z + bbv.z;
            float w3 = r0.w + r1.w + r2.w + r3.w + bbv.w;
            float* spY = out + (size_t)b * Dv * Cv + (size_t)dd * Cv;
            float* spP = spY + (size_t)Bv * Dv * Cv;
            *(float4*)spY = make_float4(w0, w1, w2, w3);
            float mx = fmaxf(fmaxf(w0, w1), fmaxf(w2, w3));
            float e0 = fexp2((w0 - mx) * L2E);
            float e1 = fexp2((w1 - mx) * L2E);
            float e2 = fexp2((w2 - mx) * L2E);
            float e3 = fexp2((w3 - mx) * L2E);
            float lse = mx + flog2(e0 + e1 + e2 + e3) * LN2;
            *(float4*)spP = make_float4(w0 - lse, w1 - lse, w2 - lse, w3 - lse);
        }
    }
}

extern "C" void kernel_launch(void* const* d_in, const int* in_sizes, int n_in,
                              void* d_out, int out_size, void* d_ws, size_t ws_size,
                              hipStream_t stream) {
    const float* x  = (const float*)d_in[0];   // [B, D]
    const float* V  = (const float*)d_in[1];   // [H, D, C]
    const float* bb = (const float*)d_in[2];   // [D, C]
    const float* W  = (const float*)d_in[3];   // [H, D]
    const float* cb = (const float*)d_in[4];   // [1, H]
    float* out = (float*)d_out;                // y_hat [B*D*C] then p_hat

    char* ws = (char*)d_ws;
    unsigned short* VtA4 = (unsigned short*)ws;                 // 4 MiB
    float* WtL = (float*)(ws + (size_t)4 * 1024 * 1024);        // 2 MiB
    float* xt  = (float*)(ws + (size_t)6 * 1024 * 1024);        // 2 MiB
    float* A0  = (float*)(ws + (size_t)8 * 1024 * 1024);        // 32 MiB (K*B*H)

    k_prep2<<<1280, 256, 0, stream>>>(W, x, V, WtL, xt, VtA4);
    k_partial<<<Kv * (Bv / 8), 512, 0, stream>>>(x, WtL, A0);
    k_prefix<<<(Bv * Hv) / 256, 256, 0, stream>>>(A0, cb);
    k_main<<<Kv * 32, 256, 0, stream>>>(xt, bb, VtA4, WtL, A0, out);
}

// Round 19
// 162.261 us; speedup vs baseline: 1.1529x; 1.0038x over previous
//
#include <hip/hip_runtime.h>

// NADE forward, B=512, D=1024, H=512, C=4.
// FINAL: best verified pieces, all verbatim:
//   1) k_prepW : W->WtL transpose (*log2e)             [R7, 128 blocks, ~2us]
//   2) k_mid   : partial sums A0 (2048 jobs) + V->frag pack (256 jobs)
//                + x->xt transpose (128 jobs)          [R7, 2432 x 512]
//                (R3/R7 arrangement measured non-main 85.7-87.9us vs
//                 prep2-first's 88.2-90.0)
//   3) k_prefix: exclusive prefix, 32 loads preloaded  [R15]
//   4) k_main  : 16 d-steps/barrier (2 barriers/chunk) [R18, 72.8us, VGPR 60]
// Session ledger (18 rounds): launch consolidation -2.7; barrier cadence
// 16->8->4->2 = -6.8 on k_main; prefix-MLP -1. Closed-negative: cooperative
// fusion (harness drops it), cross-barrier prefetch (spill), waves-arg=8
// (32-VGPR budget spill), fine-chunks (latency, no occupancy), 8-wave k_main
// (+7.4, not residency-bound), partial+prefix fusion x2 (parallelism /
// line-amp), prefix-in-prologue (O(K^2) L3), A0 relayout, W-direct reads,
// launch repacking x2 (neutral). k_main floor: trans-pipe sigmoid issue.

#define Bv 512
#define Dv 1024
#define Hv 512
#define Cv 4
#define Kv 32
#define DCv 32   // Dv / Kv

#define L2E 1.4426950408889634f
#define LN2 0.6931471805599453f

typedef __attribute__((ext_vector_type(8))) short short8;
typedef __attribute__((ext_vector_type(4))) float f32x4;

__device__ __forceinline__ float fexp2(float x) { return __builtin_amdgcn_exp2f(x); }
__device__ __forceinline__ float flog2(float x) { return __builtin_amdgcn_logf(x); }
__device__ __forceinline__ float frcp(float x)  { return __builtin_amdgcn_rcpf(x); }

// pack two f32 -> bf16x2 by truncation (1 v_perm_b32)
__device__ __forceinline__ unsigned bf16pk(float lo, float hi) {
    return __builtin_amdgcn_perm(__float_as_uint(hi), __float_as_uint(lo), 0x07060302u);
}
__device__ __forceinline__ unsigned short bf16rne(float f) {
    unsigned u = __float_as_uint(f);
    return (unsigned short)((u + 0x7FFFu + ((u >> 16) & 1u)) >> 16);
}

// ---- launch 1: W -> WtL (transpose, *log2e). 128 tiles of 64x64. ----
__global__ __launch_bounds__(256) void k_prepW(const float* __restrict__ W,
                                               float* __restrict__ WtL) {
    __shared__ float t[64][65];
    const int tile = blockIdx.x;         // 0..127
    const int tr   = tile >> 4;          // h tile, 0..7
    const int tc   = tile & 15;          // d tile, 0..15
    const int lx = threadIdx.x & 15;
    const int ly = threadIdx.x >> 4;
#pragma unroll
    for (int r = 0; r < 64; r += 16) {
        int row = r + ly;
        float4 v = *(const float4*)(W + (size_t)(tr * 64 + row) * Dv + tc * 64 + lx * 4);
        t[row][lx * 4 + 0] = v.x;
        t[row][lx * 4 + 1] = v.y;
        t[row][lx * 4 + 2] = v.z;
        t[row][lx * 4 + 3] = v.w;
    }
    __syncthreads();
#pragma unroll
    for (int r = 0; r < 64; r += 16) {
        int row = r + ly;   // d within tile
        float4 o = make_float4(t[lx * 4 + 0][row] * L2E,
                               t[lx * 4 + 1][row] * L2E,
                               t[lx * 4 + 2][row] * L2E,
                               t[lx * 4 + 3][row] * L2E);
        *(float4*)(WtL + (size_t)(tc * 64 + row) * 512 + tr * 64 + lx * 4) = o;
    }
}

// ---- launch 2: partials + V-pack + x-transpose, role-split (R7 verbatim) ----
__global__ __launch_bounds__(512) void k_mid(
        const float* __restrict__ x, const float* __restrict__ V,
        const float* __restrict__ WtL,
        unsigned short* __restrict__ VtA4, float* __restrict__ xt,
        float* __restrict__ A0) {
    __shared__ __align__(16) char smem[16640];
    const int blk = blockIdx.x;

    if (blk < 2048) {
        // A0[k][b][h] = sum_{d in chunk k} x[b,d]*WtL[d][h]
        float* xs = (float*)smem;    // [32 d][8 b]
        const int k  = blk >> 6;
        const int bg = blk & 63;
        const int h  = threadIdx.x;
        const int d0 = k * DCv;
        if (threadIdx.x < DCv * 8) {
            int g = threadIdx.x >> 5;   // batch in group of 8
            int j = threadIdx.x & 31;   // d in chunk
            xs[j * 8 + g] = x[(size_t)(bg * 8 + g) * Dv + d0 + j];
        }
        __syncthreads();
        float acc[8];
#pragma unroll
        for (int g = 0; g < 8; ++g) acc[g] = 0.0f;
        const float* wp = WtL + (size_t)d0 * Hv + h;
        for (int j = 0; j < DCv; ++j) {
            float wv = wp[(size_t)j * Hv];
            const float4 x0 = *(const float4*)(xs + j * 8);
            const float4 x1 = *(const float4*)(xs + j * 8 + 4);
            acc[0] = fmaf(x0.x, wv, acc[0]);
            acc[1] = fmaf(x0.y, wv, acc[1]);
            acc[2] = fmaf(x0.z, wv, acc[2]);
            acc[3] = fmaf(x0.w, wv, acc[3]);
            acc[4] = fmaf(x1.x, wv, acc[4]);
            acc[5] = fmaf(x1.y, wv, acc[5]);
            acc[6] = fmaf(x1.z, wv, acc[6]);
            acc[7] = fmaf(x1.w, wv, acc[7]);
        }
#pragma unroll
        for (int g = 0; g < 8; ++g)
            A0[((size_t)k * Bv + bg * 8 + g) * Hv + h] = acc[g];
    } else if (blk < 2304) {
        // V -> VtA4 fragments (bf16 RNE), 4 d per block, 512-thread variant.
        // VtA4[((d*16 + hb)*16 + q*4 + c)*8 + j], elem = V[h=hb*32+q*8+j][d][c]
        unsigned short* tile = (unsigned short*)smem;   // 8192 shorts = 16 KiB
        const int d0  = (blk - 2048) * 4;
        const int dd  = threadIdx.x & 3;
        const int hb0 = threadIdx.x >> 2;   // 0..127 -> 128 h per pass
#pragma unroll
        for (int p = 0; p < 4; ++p) {
            int h = p * 128 + hb0;
            float4 v = *(const float4*)(V + ((size_t)h * Dv + d0 + dd) * Cv);
            int hb = h >> 5, q = (h >> 3) & 3, j = h & 7;
            int base = ((dd * 16 + hb) * 16 + q * 4) * 8 + j;
            tile[base + 0 * 8] = bf16rne(v.x);
            tile[base + 1 * 8] = bf16rne(v.y);
            tile[base + 2 * 8] = bf16rne(v.z);
            tile[base + 3 * 8] = bf16rne(v.w);
        }
        __syncthreads();
        uint4* dst = (uint4*)(VtA4 + (size_t)d0 * 2048);
        const uint4* srcp = (const uint4*)tile;
        for (int tt = threadIdx.x; tt < 1024; tt += 512) dst[tt] = srcp[tt];
    } else {
        // x -> xt transpose (scale 1), 512-thread variant of the 64x64 tile.
        float (*t)[65] = (float(*)[65])smem;
        const int tile = blk - 2304;         // 0..127
        const int tr   = tile >> 4;          // b tile
        const int tc   = tile & 15;          // d tile
        const int lx = threadIdx.x & 15;
        const int ly = threadIdx.x >> 4;     // 0..31
#pragma unroll
        for (int r = 0; r < 64; r += 32) {
            int row = r + ly;
            float4 v = *(const float4*)(x + (size_t)(tr * 64 + row) * Dv + tc * 64 + lx * 4);
            t[row][lx * 4 + 0] = v.x;
            t[row][lx * 4 + 1] = v.y;
            t[row][lx * 4 + 2] = v.z;
            t[row][lx * 4 + 3] = v.w;
        }
        __syncthreads();
#pragma unroll
        for (int r = 0; r < 64; r += 32) {
            int row = r + ly;   // d within tile
            float4 o = make_float4(t[lx * 4 + 0][row],
                                   t[lx * 4 + 1][row],
                                   t[lx * 4 + 2][row],
                                   t[lx * 4 + 3][row]);
            *(float4*)(xt + (size_t)(tc * 64 + row) * 512 + tr * 64 + lx * 4) = o;
        }
    }
}

// ---- launch 3: exclusive prefix, loads fully preloaded (R15 verbatim) ----
__global__ void k_prefix(float* __restrict__ A0, const float* __restrict__ cbias) {
    int gid = blockIdx.x * blockDim.x + threadIdx.x;   // B*H
    int h = gid & (Hv - 1);
    int bi = gid >> 9;
    float* p = A0 + (size_t)bi * Hv + h;

    float t[Kv];
#pragma unroll
    for (int k = 0; k < Kv; ++k)
        t[k] = p[(size_t)k * Bv * Hv];

    float run = cbias[h] * L2E;
#pragma unroll
    for (int k = 0; k < Kv; ++k) {
        p[(size_t)k * Bv * Hv] = run;
        run += t[k];
    }
}

// ---- launch 4: main scan, 16 d-steps per barrier (R18 verbatim, 72.8us). ----
__global__ __launch_bounds__(256, 4) void k_main(
        const float* __restrict__ xt, const float* __restrict__ bbias,
        const unsigned short* __restrict__ VtA4, const float* __restrict__ WtL,
        const float* __restrict__ A0, float* __restrict__ out) {
    const int k    = blockIdx.x >> 5;
    const int bg   = blockIdx.x & 31;
    const int wid  = threadIdx.x >> 6;   // H-slice owner
    const int lane = threadIdx.x & 63;
    const int bl   = lane & 15;          // batch col (B-op) / class row m (A-op)
    const int quad = lane >> 4;
    const int b    = bg * 16 + bl;
    const int d0   = k * DCv;

    // only quad==0 lanes carry nonzero C rows (A rows 4..15 are zero)
    __shared__ f32x4 red[2][16][4][16];  // [buf][step][wid][batch], 32 KiB

    // a state: h = wid*128 + kb*32 + quad*8 + j (scaled domain)
    float a[32];
    {
        const float* ap = A0 + ((size_t)k * Bv + b) * Hv + wid * 128 + quad * 8;
#pragma unroll
        for (int kb = 0; kb < 4; ++kb) {
            float4 t0 = *(const float4*)(ap + kb * 32);
            float4 t1 = *(const float4*)(ap + kb * 32 + 4);
            a[kb*8+0]=t0.x; a[kb*8+1]=t0.y; a[kb*8+2]=t0.z; a[kb*8+3]=t0.w;
            a[kb*8+4]=t1.x; a[kb*8+5]=t1.y; a[kb*8+6]=t1.z; a[kb*8+7]=t1.w;
        }
    }

    const bool act = (bl < 4);
    const unsigned short* vp = VtA4 + (((size_t)d0 * 16 + wid * 4) * 16 + quad * 4 + bl) * 8;
    const float* wp = WtL + (size_t)d0 * Hv + wid * 128 + quad * 8;
    const float* xp = xt + (size_t)d0 * Bv + b;

    const short8 zfrag = {0,0,0,0,0,0,0,0};

    for (int i1 = 0; i1 < 2; ++i1) {             // 2 iterations, 1 barrier each
        const int buf = i1 & 1;
#pragma unroll 1
        for (int q4 = 0; q4 < 4; ++q4) {
#pragma unroll
            for (int s = 0; s < 4; ++s) {
                // this step's fragments + scalar (one step live at a time)
                short8 af[4];
#pragma unroll
                for (int kb = 0; kb < 4; ++kb)
                    af[kb] = act ? *(const short8*)(vp + s * 2048 + kb * 128) : zfrag;
                float xd = xp[s * Bv];

                // sigmoid + pack
                unsigned pk[16];
#pragma unroll
                for (int m = 0; m < 32; m += 2) {
                    float s0 = frcp(1.0f + fexp2(-a[m]));
                    float s1 = frcp(1.0f + fexp2(-a[m + 1]));
                    pk[m >> 1] = bf16pk(s0, s1);
                }
                // MFMA over the wave's 128-h slice
                f32x4 acc = {0.f, 0.f, 0.f, 0.f};
#pragma unroll
                for (int kb = 0; kb < 4; ++kb) {
                    union { unsigned u[4]; short8 s8; } cv;
                    cv.u[0] = pk[kb*4+0]; cv.u[1] = pk[kb*4+1];
                    cv.u[2] = pk[kb*4+2]; cv.u[3] = pk[kb*4+3];
                    acc = __builtin_amdgcn_mfma_f32_16x16x32_bf16(af[kb], cv.s8, acc, 0, 0, 0);
                }
                // advance a to next step
#pragma unroll
                for (int kb = 0; kb < 4; ++kb)
#pragma unroll
                    for (int j = 0; j < 8; ++j)
                        a[kb*8+j] = fmaf(xd, wp[s * Hv + kb*32 + j], a[kb*8+j]);

                if (quad == 0) red[buf][q4 * 4 + s][wid][bl] = acc;
            }
            vp += 4 * 2048;
            wp += 4 * Hv;
            xp += 4 * Bv;
        }
        __syncthreads();

        // ---- epilogue: 16 steps, all 64 lanes: quad q -> step wid*4+q ----
        {
            const int sE = wid * 4 + quad;          // 0..15
            const int dd = d0 + i1 * 16 + sE;       // global d of this step
            float4 bbv = *(const float4*)(bbias + dd * Cv);
            f32x4 r0 = red[buf][sE][0][bl];
            f32x4 r1 = red[buf][sE][1][bl];
            f32x4 r2 = red[buf][sE][2][bl];
            f32x4 r3 = red[buf][sE][3][bl];
            float w0 = r0.x + r1.x + r2.x + r3.x + bbv.x;
            float w1 = r0.y + r1.y + r2.y + r3.y + bbv.y;
            float w2 = r0.z + r1.z + r2.z + r3.z + bbv.z;
            float w3 = r0.w + r1.w + r2.w + r3.w + bbv.w;
            float* spY = out + (size_t)b * Dv * Cv + (size_t)dd * Cv;
            float* spP = spY + (size_t)Bv * Dv * Cv;
            *(float4*)spY = make_float4(w0, w1, w2, w3);
            float mx = fmaxf(fmaxf(w0, w1), fmaxf(w2, w3));
            float e0 = fexp2((w0 - mx) * L2E);
            float e1 = fexp2((w1 - mx) * L2E);
            float e2 = fexp2((w2 - mx) * L2E);
            float e3 = fexp2((w3 - mx) * L2E);
            float lse = mx + flog2(e0 + e1 + e2 + e3) * LN2;
            *(float4*)spP = make_float4(w0 - lse, w1 - lse, w2 - lse, w3 - lse);
        }
    }
}

extern "C" void kernel_launch(void* const* d_in, const int* in_sizes, int n_in,
                              void* d_out, int out_size, void* d_ws, size_t ws_size,
                              hipStream_t stream) {
    const float* x  = (const float*)d_in[0];   // [B, D]
    const float* V  = (const float*)d_in[1];   // [H, D, C]
    const float* bb = (const float*)d_in[2];   // [D, C]
    const float* W  = (const float*)d_in[3];   // [H, D]
    const float* cb = (const float*)d_in[4];   // [1, H]
    float* out = (float*)d_out;                // y_hat [B*D*C] then p_hat

    char* ws = (char*)d_ws;
    unsigned short* VtA4 = (unsigned short*)ws;                 // 4 MiB
    float* WtL = (float*)(ws + (size_t)4 * 1024 * 1024);        // 2 MiB
    float* xt  = (float*)(ws + (size_t)6 * 1024 * 1024);        // 2 MiB
    float* A0  = (float*)(ws + (size_t)8 * 1024 * 1024);        // 32 MiB (K*B*H)

    k_prepW<<<128, 256, 0, stream>>>(W, WtL);
    k_mid<<<2432, 512, 0, stream>>>(x, V, WtL, VtA4, xt, A0);
    k_prefix<<<(Bv * Hv) / 256, 256, 0, stream>>>(A0, cb);
    k_main<<<Kv * 32, 256, 0, stream>>>(xt, bb, VtA4, WtL, A0, out);
}